// Round 7
// baseline (494.510 us; speedup 1.0000x reference)
//
#include <hip/hip_runtime.h>
#include <hip/hip_bf16.h>

typedef __attribute__((ext_vector_type(8))) short bf16x8;
typedef __attribute__((ext_vector_type(4))) float floatx4;

#define B_ 32
#define S_ 512
#define H_ 512
#define M_ (B_*S_)       // 16384 rows
#define K_ 512
#define N_ 1024          // 2H

// async global->LDS, 16B per lane, LDS dest = wave-uniform base + lane*16
__device__ __forceinline__ void gload_lds16(const void* g, void* l) {
  __builtin_amdgcn_global_load_lds(
      (const __attribute__((address_space(1))) void*)g,
      (__attribute__((address_space(3))) void*)l, 16, 0, 0);
}

// ---------------- fp32 -> bf16 weight convert (both W tensors, one launch) ----
__global__ void cvt2_kernel(const float* __restrict__ s0, const float* __restrict__ s1,
                            __hip_bfloat16* __restrict__ d0, __hip_bfloat16* __restrict__ d1) {
  int t = blockIdx.x * 256 + threadIdx.x;      // [0, 1048576)
  const float* src;
  __hip_bfloat16* dst;
  int i;
  if (t < 524288) { src = s0; dst = d0; i = t; }
  else            { src = s1; dst = d1; i = t - 524288; }
  float4 v = *(const float4*)(src + (size_t)i * 4);
  union { ushort4 u; __hip_bfloat16 h[4]; } pk;
  pk.h[0] = __float2bfloat16(v.x);
  pk.h[1] = __float2bfloat16(v.y);
  pk.h[2] = __float2bfloat16(v.z);
  pk.h[3] = __float2bfloat16(v.w);
  *(ushort4*)((unsigned short*)dst + (size_t)i * 4) = pk.u;
}

// ---------------- window conv (both dirs), writes bf16 x only ----------------
__global__ void conv_kernel(const float* __restrict__ inf, const float* __restrict__ inb,
                            int instride,
                            const float* __restrict__ fpad, const float* __restrict__ bpad,
                            const float* __restrict__ fw, const float* __restrict__ bw,
                            __hip_bfloat16* __restrict__ xaf, __hip_bfloat16* __restrict__ xab) {
  int t = blockIdx.x * 256 + threadIdx.x;      // 0 .. M_*128-1
  int dir = blockIdx.y;
  int row = t >> 7;                            // 0..16383  (= b*S + s)
  int hv  = (t & 127) << 2;                    // h, float4-vectorized
  int s = row & (S_ - 1);
  float4 a = make_float4(0.f, 0.f, 0.f, 0.f);
  if (dir == 0) {
#pragma unroll
    for (int k = 0; k < 5; ++k) {
      float w = fw[k];
      const float* src = (s + k < 4) ? (fpad + (size_t)(s + k) * H_ + hv)
                                     : (inf + (size_t)(row + k - 4) * instride + hv);
      float4 v = *(const float4*)src;
      a.x += w * v.x; a.y += w * v.y; a.z += w * v.z; a.w += w * v.w;
    }
  } else {
#pragma unroll
    for (int k = 0; k < 5; ++k) {
      float w = bw[k];
      const float* src = (s + k < S_) ? (inb + (size_t)(row + k) * instride + hv)
                                      : (bpad + (size_t)(s + k - S_) * H_ + hv);
      float4 v = *(const float4*)src;
      a.x += w * v.x; a.y += w * v.y; a.z += w * v.z; a.w += w * v.w;
    }
  }
  __hip_bfloat16* xa = dir ? xab : xaf;
  union { ushort4 u; __hip_bfloat16 h[4]; } pk;
  pk.h[0] = __float2bfloat16(a.x);
  pk.h[1] = __float2bfloat16(a.y);
  pk.h[2] = __float2bfloat16(a.z);
  pk.h[3] = __float2bfloat16(a.w);
  *(ushort4*)((unsigned short*)xa + (size_t)row * H_ + hv) = pk.u;
}

// -------- fused highway GEMM: double-buffered 2-phase AT 2 blocks/CU --------
// Merges the two best measured structures (one mechanism each):
//   r3 (best, 422us): 2-phase dbuf K-loop, 1 block/CU   -> intra-block overlap
//   r6 (440us):       single-buf, 2 blocks/CU           -> cross-block overlap
// This build: BOTH. 512 thr (8 waves, 2M x 4N), tile 128 rows x 256 proj
// (=128 out cols: nonlin [h0,h0+128) + gate [512+h0,..)). BK=32, dbuf LDS =
// 2 x (A[128x32]+B[256x32]) = 48KB; acc 4x4 floatx4 = 64 VGPR;
// __launch_bounds__(512,4) -> <=128 VGPR -> 16 waves/CU = 2 RESIDENT BLOCKS
// with INDEPENDENT barriers (r5's 16-wave single-barrier lockstep was -9%).
// Schedule per K-step (r3-verbatim): issue next tile's 3 gload_lds/wave ->
// snapshot/ds_read/16 MFMA on current -> one __syncthreads (vmcnt drain).
// Swizzle (r3/r5-verified, BK=32): LDS 8-elem slot s of row r holds k-chunk
// s^((r>>1)&3); staging SOURCE k-offset permuted (gload_lds dest linear);
// read slot = quad^((l16>>1)&3) -> 2-way max (free, conflicts measured 0).
// B rows remapped (r6-verified): wave wn's j=0,1 -> nonlin cols wn*32+j*16+l16,
// j=2,3 -> gate of the same cols; epilogue pairing wave-local.
// XCD remap: 4 bx-siblings of an A-panel share n&7 -> same XCD L2.
// Epilogue stages output tile through dead LDS -> full-line HBM writes.
__global__ __launch_bounds__(512, 4)
void hw_gemm(const __hip_bfloat16* __restrict__ Af, const __hip_bfloat16* __restrict__ Ab,
             const __hip_bfloat16* __restrict__ Wf, const __hip_bfloat16* __restrict__ Wb,
             const float* __restrict__ biasf, const float* __restrict__ biasb,
             __hip_bfloat16* __restrict__ Anf, __hip_bfloat16* __restrict__ Anb,
             float* __restrict__ outp, int final_mode) {
  __shared__ __align__(16) char smem[49152];   // buf{0,1} x {A 8KB | B 16KB}

  const int tid = threadIdx.x;
  const int lane = tid & 63, wave = tid >> 6;    // 8 waves
  const int wm = wave >> 2, wn = wave & 3;       // 2M x 4N
  const int quad = lane >> 4, l16 = lane & 15;
  const int dir = blockIdx.z;

  const int n = blockIdx.x;                      // [0,512)
  const int mpanel = (n & 7) | ((n >> 5) << 3);  // [0,128); bx-siblings share n&7
  const int bx = (n >> 3) & 3;
  const int m0 = mpanel * 128;
  const int h0 = bx * 128;                       // out-col base

  const __hip_bfloat16* A = dir ? Ab : Af;
  const __hip_bfloat16* Wm = dir ? Wb : Wf;
  const float* bias = dir ? biasb : biasf;
  __hip_bfloat16* An = dir ? Anb : Anf;

  floatx4 acc[4][4];   // [m][j: 0,1 nonlin  2,3 gate] = 64 VGPR
#pragma unroll
  for (int i = 0; i < 4; ++i)
#pragma unroll
    for (int j = 0; j < 4; ++j) acc[i][j] = (floatx4){0.f, 0.f, 0.f, 0.f};

  const int srow = lane >> 2;                    // row within 16-row chunk
  const int skk  = (((lane & 3) ^ ((lane >> 3) & 3)) << 3);  // swizzled src k off
  const int key  = (l16 >> 1) & 3;               // read-side swizzle key
  const int xkp  = bx * 4 + wn;                  // K-tile with this wave's x cols

  // staging: 1 A-chunk + 2 B-chunks per wave (16 rows each)
  const __hip_bfloat16* aptr = A + (size_t)(m0 + wave * 16 + srow) * K_ + skk;
  const __hip_bfloat16* bptr[2];
#pragma unroll
  for (int c = 0; c < 2; ++c) {
    const int brow = (wave * 2 + c) * 16 + srow; // LDS B row [0,256)
    const int wnp = brow >> 6, rr = brow & 63;   // owner wave-col, row within
    const int wrow = (rr < 32) ? (h0 + wnp * 32 + rr)                // nonlin
                               : (512 + h0 + wnp * 32 + (rr - 32));  // gate
    bptr[c] = Wm + (size_t)wrow * K_ + skk;
  }

  // prologue: stage K-tile 0 into buffer 0
  gload_lds16(aptr, smem + wave * 1024);
  gload_lds16(bptr[0], smem + 8192 + (wave * 2) * 1024);
  gload_lds16(bptr[1], smem + 8192 + (wave * 2 + 1) * 1024);
  __syncthreads();

  unsigned int xsp[4][2][2];   // residual x, bf16-packed row pairs (static idx)
  int cur = 0;
  for (int kp = 0; kp < 16; ++kp) {
    const __hip_bfloat16* cA = (const __hip_bfloat16*)(smem + cur * 24576);
    const __hip_bfloat16* cB = (const __hip_bfloat16*)(smem + cur * 24576 + 8192);
    // issue next K-tile's loads into the other buffer (lands at end-of-iter barrier)
    if (kp < 15) {
      char* nb = smem + (cur ^ 1) * 24576;
      const int kb = (kp + 1) * 32;
      gload_lds16(aptr + kb, nb + wave * 1024);
      gload_lds16(bptr[0] + kb, nb + 8192 + (wave * 2) * 1024);
      gload_lds16(bptr[1] + kb, nb + 8192 + (wave * 2 + 1) * 1024);
    }
    if (kp == xkp) {             // snapshot this wave's 32 x cols (one K-tile)
      const unsigned short* pA = (const unsigned short*)cA;
#pragma unroll
      for (int i = 0; i < 4; ++i)
#pragma unroll
        for (int jj = 0; jj < 2; ++jj)
#pragma unroll
          for (int rh = 0; rh < 2; ++rh) {
            const int ra0 = wm * 64 + i * 16 + quad * 4 + rh * 2;
            const int ra1 = ra0 + 1;
            const int c2 = jj * 16 + l16;
            unsigned int lo = pA[ra0 * 32 + ((((c2 >> 3) ^ ((ra0 >> 1) & 3)) << 3) | (c2 & 7))];
            unsigned int hi = pA[ra1 * 32 + ((((c2 >> 3) ^ ((ra1 >> 1) & 3)) << 3) | (c2 & 7))];
            xsp[i][jj][rh] = lo | (hi << 16);
          }
    }
    // compute: 16 MFMA/wave (K=32)
    bf16x8 av[4], bv[4];
#pragma unroll
    for (int i = 0; i < 4; ++i) {
      const int ra = wm * 64 + i * 16 + l16;
      av[i] = *(const bf16x8*)&cA[ra * 32 + ((quad ^ key) << 3)];
    }
#pragma unroll
    for (int j = 0; j < 4; ++j) {
      const int rb = wn * 64 + j * 16 + l16;
      bv[j] = *(const bf16x8*)&cB[rb * 32 + ((quad ^ key) << 3)];
    }
#pragma unroll
    for (int i = 0; i < 4; ++i)
#pragma unroll
      for (int j = 0; j < 4; ++j)
        acc[i][j] = __builtin_amdgcn_mfma_f32_16x16x32_bf16(av[i], bv[j], acc[i][j], 0, 0, 0);

    __syncthreads();   // drains vmcnt (next tile staged) + all reads of cur done
    cur ^= 1;
  }
  // smem (48KB) is dead now -> reuse as epilogue output tile

  float bnl[2], bgt[2];
#pragma unroll
  for (int j = 0; j < 2; ++j) {
    const int c = h0 + wn * 32 + j * 16 + l16;
    bnl[j] = bias[c];
    bgt[j] = bias[512 + c];
  }

  if (final_mode) {
    // fp32 [128][64] per col-half = 32KB; two passes, full-line (2x128B/row) stores
    float* ft = (float*)smem;
#pragma unroll
    for (int p = 0; p < 2; ++p) {
      if ((wn >> 1) == p) {
#pragma unroll
        for (int i = 0; i < 4; ++i)
#pragma unroll
          for (int r = 0; r < 4; ++r) {
            const int rl = wm * 64 + i * 16 + quad * 4 + r;
#pragma unroll
            for (int j = 0; j < 2; ++j) {
              float pn = acc[i][j][r] + bnl[j];
              float pg = acc[i][j + 2][r] + bgt[j];
              float g = 1.f / (1.f + __expf(-pg));
              unsigned int u = xsp[i][j][r >> 1];
              unsigned int bits = (r & 1) ? (u >> 16) : (u & 0xffffu);
              float xo = __uint_as_float(bits << 16);
              ft[rl * 64 + (wn & 1) * 32 + j * 16 + l16] =
                  g * xo + (1.f - g) * fmaxf(pn, 0.f);
            }
          }
      }
      __syncthreads();
#pragma unroll
      for (int q = 0; q < 4; ++q) {
        const int rl = q * 32 + (tid >> 4);
        const int cc = (tid & 15) * 4;
        float4 v = *(const float4*)&ft[rl * 64 + cc];
        *(float4*)&outp[(size_t)(m0 + rl) * N_ + dir * H_ + h0 + p * 64 + cc] = v;
      }
      __syncthreads();
    }
  } else {
    // bf16 [128][128] = 32KB; one pass, full-line (2x128B/row) stores
    __hip_bfloat16* bt = (__hip_bfloat16*)smem;
#pragma unroll
    for (int i = 0; i < 4; ++i)
#pragma unroll
      for (int r = 0; r < 4; ++r) {
        const int rl = wm * 64 + i * 16 + quad * 4 + r;
#pragma unroll
        for (int j = 0; j < 2; ++j) {
          float pn = acc[i][j][r] + bnl[j];
          float pg = acc[i][j + 2][r] + bgt[j];
          float g = 1.f / (1.f + __expf(-pg));
          unsigned int u = xsp[i][j][r >> 1];
          unsigned int bits = (r & 1) ? (u >> 16) : (u & 0xffffu);
          float xo = __uint_as_float(bits << 16);
          bt[rl * 128 + wn * 32 + j * 16 + l16] =
              __float2bfloat16(g * xo + (1.f - g) * fmaxf(pn, 0.f));
        }
      }
    __syncthreads();
    const unsigned short* src = (const unsigned short*)smem;
#pragma unroll
    for (int p = 0; p < 4; ++p) {
      const int rl = p * 32 + (tid >> 4);
      const int cc = (tid & 15) * 8;             // 8 bf16 = 16B per lane
      int4 v = *(const int4*)(src + rl * 128 + cc);
      *(int4*)((unsigned short*)An + (size_t)(m0 + rl) * H_ + h0 + cc) = v;
    }
  }
}

extern "C" void kernel_launch(void* const* d_in, const int* in_sizes, int n_in,
                              void* d_out, int out_size, void* d_ws, size_t ws_size,
                              hipStream_t stream) {
  const float* inputs   = (const float*)d_in[0];
  // d_in[1] = masks (unused by reference)
  const float* fwd_pads = (const float*)d_in[2];
  const float* bwd_pads = (const float*)d_in[3];
  const float* fwd_ws_p = (const float*)d_in[4];
  const float* bwd_ws_p = (const float*)d_in[5];
  const float* fwd_hw_W = (const float*)d_in[6];
  const float* fwd_hw_b = (const float*)d_in[7];
  const float* bwd_hw_W = (const float*)d_in[8];
  const float* bwd_hw_b = (const float*)d_in[9];
  float* out = (float*)d_out;

  char* ws = (char*)d_ws;
  size_t off = 0;
  __hip_bfloat16* Wbf = (__hip_bfloat16*)(ws + off); off += (size_t)4194304 * 2;  // 8 matrices [1024,512]
  __hip_bfloat16* xa0f = (__hip_bfloat16*)(ws + off); off += (size_t)M_ * H_ * 2;
  __hip_bfloat16* xa0b = (__hip_bfloat16*)(ws + off); off += (size_t)M_ * H_ * 2;
  __hip_bfloat16* xa1f = (__hip_bfloat16*)(ws + off); off += (size_t)M_ * H_ * 2;
  __hip_bfloat16* xa1b = (__hip_bfloat16*)(ws + off); off += (size_t)M_ * H_ * 2;
  // total ~75 MiB

  // weights -> bf16 (fwd at 0, bwd at +2097152 elements), single launch
  cvt2_kernel<<<4096, 256, 0, stream>>>(fwd_hw_W, bwd_hw_W, Wbf, Wbf + (size_t)2097152);

  for (int l = 0; l < 2; ++l) {
    const float *inf, *inb;
    int instride;
    if (l == 0) { inf = inputs; inb = inputs; instride = H_; }
    else        { inf = out;    inb = out + H_; instride = N_; }  // read layer-0 output
    conv_kernel<<<dim3(8192, 2), 256, 0, stream>>>(
        inf, inb, instride,
        fwd_pads + (size_t)l * 4 * H_, bwd_pads + (size_t)l * 4 * H_,
        fwd_ws_p + l * 5, bwd_ws_p + l * 5,
        xa0f, xa0b);

    // highway iter 0 (writes bf16 x ping)
    hw_gemm<<<dim3(512, 1, 2), 512, 0, stream>>>(
        xa0f, xa0b,
        Wbf + (size_t)(l * 2) * 524288, Wbf + (size_t)2097152 + (size_t)(l * 2) * 524288,
        fwd_hw_b + (l * 2) * 1024, bwd_hw_b + (l * 2) * 1024,
        xa1f, xa1b, nullptr, 0);

    // highway iter 1 (final: writes d_out[l])
    hw_gemm<<<dim3(512, 1, 2), 512, 0, stream>>>(
        xa1f, xa1b,
        Wbf + (size_t)(l * 2 + 1) * 524288, Wbf + (size_t)2097152 + (size_t)(l * 2 + 1) * 524288,
        fwd_hw_b + (l * 2 + 1) * 1024, bwd_hw_b + (l * 2 + 1) * 1024,
        nullptr, nullptr, out + (size_t)l * M_ * N_, 1);
  }
}

// Round 8
// 420.685 us; speedup vs baseline: 1.1755x; 1.1755x over previous
//
#include <hip/hip_runtime.h>
#include <hip/hip_bf16.h>

typedef __attribute__((ext_vector_type(8))) short bf16x8;
typedef __attribute__((ext_vector_type(4))) float floatx4;

#define B_ 32
#define S_ 512
#define H_ 512
#define M_ (B_*S_)       // 16384 rows
#define K_ 512
#define N_ 1024          // 2H

// async global->LDS, 16B per lane, LDS dest = wave-uniform base + lane*16
__device__ __forceinline__ void gload_lds16(const void* g, void* l) {
  __builtin_amdgcn_global_load_lds(
      (const __attribute__((address_space(1))) void*)g,
      (__attribute__((address_space(3))) void*)l, 16, 0, 0);
}

// ---------------- fp32 -> bf16 weight convert (both W tensors, one launch) ----
__global__ void cvt2_kernel(const float* __restrict__ s0, const float* __restrict__ s1,
                            __hip_bfloat16* __restrict__ d0, __hip_bfloat16* __restrict__ d1) {
  int t = blockIdx.x * 256 + threadIdx.x;      // [0, 1048576)
  const float* src;
  __hip_bfloat16* dst;
  int i;
  if (t < 524288) { src = s0; dst = d0; i = t; }
  else            { src = s1; dst = d1; i = t - 524288; }
  float4 v = *(const float4*)(src + (size_t)i * 4);
  union { ushort4 u; __hip_bfloat16 h[4]; } pk;
  pk.h[0] = __float2bfloat16(v.x);
  pk.h[1] = __float2bfloat16(v.y);
  pk.h[2] = __float2bfloat16(v.z);
  pk.h[3] = __float2bfloat16(v.w);
  *(ushort4*)((unsigned short*)dst + (size_t)i * 4) = pk.u;
}

// ---------------- window conv (both dirs), writes bf16 x only ----------------
__global__ void conv_kernel(const float* __restrict__ inf, const float* __restrict__ inb,
                            int instride,
                            const float* __restrict__ fpad, const float* __restrict__ bpad,
                            const float* __restrict__ fw, const float* __restrict__ bw,
                            __hip_bfloat16* __restrict__ xaf, __hip_bfloat16* __restrict__ xab) {
  int t = blockIdx.x * 256 + threadIdx.x;      // 0 .. M_*128-1
  int dir = blockIdx.y;
  int row = t >> 7;                            // 0..16383  (= b*S + s)
  int hv  = (t & 127) << 2;                    // h, float4-vectorized
  int s = row & (S_ - 1);
  float4 a = make_float4(0.f, 0.f, 0.f, 0.f);
  if (dir == 0) {
#pragma unroll
    for (int k = 0; k < 5; ++k) {
      float w = fw[k];
      const float* src = (s + k < 4) ? (fpad + (size_t)(s + k) * H_ + hv)
                                     : (inf + (size_t)(row + k - 4) * instride + hv);
      float4 v = *(const float4*)src;
      a.x += w * v.x; a.y += w * v.y; a.z += w * v.z; a.w += w * v.w;
    }
  } else {
#pragma unroll
    for (int k = 0; k < 5; ++k) {
      float w = bw[k];
      const float* src = (s + k < S_) ? (inb + (size_t)(row + k) * instride + hv)
                                      : (bpad + (size_t)(s + k - S_) * H_ + hv);
      float4 v = *(const float4*)src;
      a.x += w * v.x; a.y += w * v.y; a.z += w * v.z; a.w += w * v.w;
    }
  }
  __hip_bfloat16* xa = dir ? xab : xaf;
  union { ushort4 u; __hip_bfloat16 h[4]; } pk;
  pk.h[0] = __float2bfloat16(a.x);
  pk.h[1] = __float2bfloat16(a.y);
  pk.h[2] = __float2bfloat16(a.z);
  pk.h[3] = __float2bfloat16(a.w);
  *(ushort4*)((unsigned short*)xa + (size_t)row * H_ + hv) = pk.u;
}

// ---------------- fused highway GEMM, 2-phase double-buffered ----------------
// R3-EXACT REVERT (measured session best: 422.4us total). Rounds 4-7 A/B'd
// counted-vmcnt, 16-wave occupancy, 2-blocks/CU single-buf, and 2-blocks/CU
// dbuf small-tile — ALL regressed (428/461/440/494). This 256x256-proj,
// BK=32-dbuf, 8-wave, 1-block/CU structure is the measured local optimum.
// 512 threads (8 waves, 4M x 2N). Tile: 256 rows x 256 proj cols
// (= 128 out cols: nonlin [h0,h0+128) paired with gate [512+h0,...)).
// BK=32 -> per-K-tile LDS = A[256x32] + B[256x32] bf16 = 32KB; double-buffered
// = 64KB STATIC shared (no dynamic-LDS opt-in / hipFuncSetAttribute).
// 2-phase: issue next K-tile's global_load_lds BEFORE ds_read+MFMA of current;
// the single end-of-iter __syncthreads (vmcnt-0 drain) publishes it.
// Swizzle: key = (row>>1)&3; LDS slot s of row r holds global k-chunk s^key;
// staging SOURCE k-offset permuted (gload_lds dest is linear);
// read slot = quad^key. (r7 counters: ~524K conflict-cycles/dispatch = ~1% -
// negligible; not worth changing.)
// B-tile rows remapped: each wave's 8 j-subtiles = 4 nonlin + 4 gate of the SAME
// out cols -> epilogue pairing wave-local.
// Epilogue stages output through the (dead) LDS -> full-line HBM writes
// (without it: 3.8x/1.9x write amplification, measured round 0).
__global__ __launch_bounds__(512, 2)
void hw_gemm(const __hip_bfloat16* __restrict__ Af, const __hip_bfloat16* __restrict__ Ab,
             const __hip_bfloat16* __restrict__ Wf, const __hip_bfloat16* __restrict__ Wb,
             const float* __restrict__ biasf, const float* __restrict__ biasb,
             __hip_bfloat16* __restrict__ Anf, __hip_bfloat16* __restrict__ Anb,
             float* __restrict__ outp, int final_mode) {
  __shared__ __align__(16) char smem[65536];   // buf0 {A 16K | B 16K} | buf1 {A | B}

  const int tid = threadIdx.x;
  const int lane = tid & 63, wave = tid >> 6;    // 8 waves
  const int wm = wave >> 1, wn = wave & 1;       // 4M x 2N
  const int quad = lane >> 4, l16 = lane & 15;
  const int dir = blockIdx.z;

  const int n = blockIdx.x;                      // [0,256)
  const int by = n & 63, bx = n >> 6;            // h-siblings share (n&7) -> same XCD
  const int m0 = by * 256;
  const int h0 = bx * 128;                       // out-col base

  const __hip_bfloat16* A = dir ? Ab : Af;
  const __hip_bfloat16* Wm = dir ? Wb : Wf;
  const float* bias = dir ? biasb : biasf;
  __hip_bfloat16* An = dir ? Anb : Anf;

  floatx4 acc[4][8];   // [m][j: 0..3 nonlin, 4..7 gate]
#pragma unroll
  for (int i = 0; i < 4; ++i)
#pragma unroll
    for (int j = 0; j < 8; ++j) acc[i][j] = (floatx4){0.f, 0.f, 0.f, 0.f};

  const int srow = lane >> 2;                    // row within 16-row staging chunk
  const int skk  = (((lane & 3) ^ ((lane >> 3) & 3)) << 3);  // swizzled src k offset
  const int key  = (l16 >> 1) & 3;               // read-side swizzle key
  const int xkp0 = bx * 4 + wn * 2;              // K-tiles holding this wave's x cols
  const int xkp1 = xkp0 + 1;

  // hoisted staging base pointers (2 A-chunks + 2 B-chunks per wave, 16 rows each)
  const __hip_bfloat16* aptr[2];
  const __hip_bfloat16* bptr[2];
#pragma unroll
  for (int c = 0; c < 2; ++c) {
    const int chunk = wave * 2 + c;              // [0,16): rows chunk*16..+16
    aptr[c] = A + (size_t)(m0 + chunk * 16 + srow) * K_ + skk;
    const int brow = chunk * 16 + srow;          // LDS B row
    const int wnp = brow >> 7, rr = brow & 127;  // wave-half, row within
    const int wrow = (rr < 64) ? (h0 + wnp * 64 + rr)                // nonlin W row
                               : (512 + h0 + wnp * 64 + (rr - 64));  // gate W row
    bptr[c] = Wm + (size_t)wrow * K_ + skk;
  }

  // prologue: stage K-tile 0 into buffer 0
#pragma unroll
  for (int c = 0; c < 2; ++c) {
    const int chunk = wave * 2 + c;
    gload_lds16(aptr[c], smem + chunk * 1024);
    gload_lds16(bptr[c], smem + 16384 + chunk * 1024);
  }
  __syncthreads();

  unsigned int xsp[4][4][2];   // residual x, bf16-packed row pairs — ALL indices static
  int cur = 0;
  for (int kp = 0; kp < 16; ++kp) {
    const __hip_bfloat16* cA = (const __hip_bfloat16*)(smem + (cur << 15));
    const __hip_bfloat16* cB = (const __hip_bfloat16*)(smem + (cur << 15) + 16384);
    // issue next K-tile's loads into the other buffer (lands at end-of-iter barrier)
    if (kp < 15) {
      char* nb = smem + ((cur ^ 1) << 15);
      const int kb = (kp + 1) * 32;
#pragma unroll
      for (int c = 0; c < 2; ++c) {
        const int chunk = wave * 2 + c;
        gload_lds16(aptr[c] + kb, nb + chunk * 1024);
        gload_lds16(bptr[c] + kb, nb + 16384 + chunk * 1024);
      }
    }
    if (kp == xkp0) {            // snapshot x cols [0,32) of this wave (j=0,1)
      const unsigned short* pA = (const unsigned short*)cA;
#pragma unroll
      for (int i = 0; i < 4; ++i)
#pragma unroll
        for (int jj = 0; jj < 2; ++jj)
#pragma unroll
          for (int rh = 0; rh < 2; ++rh) {
            const int ra0 = wm * 64 + i * 16 + quad * 4 + rh * 2;
            const int ra1 = ra0 + 1;
            const int c2 = jj * 16 + l16;
            unsigned int lo = pA[ra0 * 32 + ((((c2 >> 3) ^ ((ra0 >> 1) & 3)) << 3) | (c2 & 7))];
            unsigned int hi = pA[ra1 * 32 + ((((c2 >> 3) ^ ((ra1 >> 1) & 3)) << 3) | (c2 & 7))];
            xsp[i][jj][rh] = lo | (hi << 16);
          }
    }
    if (kp == xkp1) {            // snapshot x cols [32,64) (j=2,3)
      const unsigned short* pA = (const unsigned short*)cA;
#pragma unroll
      for (int i = 0; i < 4; ++i)
#pragma unroll
        for (int jj = 0; jj < 2; ++jj)
#pragma unroll
          for (int rh = 0; rh < 2; ++rh) {
            const int ra0 = wm * 64 + i * 16 + quad * 4 + rh * 2;
            const int ra1 = ra0 + 1;
            const int c2 = jj * 16 + l16;
            unsigned int lo = pA[ra0 * 32 + ((((c2 >> 3) ^ ((ra0 >> 1) & 3)) << 3) | (c2 & 7))];
            unsigned int hi = pA[ra1 * 32 + ((((c2 >> 3) ^ ((ra1 >> 1) & 3)) << 3) | (c2 & 7))];
            xsp[i][2 + jj][rh] = lo | (hi << 16);
          }
    }
    // compute: 32 MFMA/wave (K=32), bv in two halves of 4 to cap VGPR pressure
    bf16x8 av[4];
#pragma unroll
    for (int i = 0; i < 4; ++i) {
      const int ra = wm * 64 + i * 16 + l16;
      av[i] = *(const bf16x8*)&cA[ra * 32 + ((quad ^ key) << 3)];
    }
#pragma unroll
    for (int jh = 0; jh < 2; ++jh) {
      bf16x8 bv[4];
#pragma unroll
      for (int jj = 0; jj < 4; ++jj) {
        const int rb = wn * 128 + (jh * 4 + jj) * 16 + l16;
        bv[jj] = *(const bf16x8*)&cB[rb * 32 + ((quad ^ key) << 3)];
      }
#pragma unroll
      for (int i = 0; i < 4; ++i)
#pragma unroll
        for (int jj = 0; jj < 4; ++jj)
          acc[i][jh * 4 + jj] =
              __builtin_amdgcn_mfma_f32_16x16x32_bf16(av[i], bv[jj], acc[i][jh * 4 + jj], 0, 0, 0);
    }
    __syncthreads();   // drains vmcnt (next tile staged) + all reads of cur done
    cur ^= 1;
  }
  // smem (all 64KB) is dead now -> reuse as epilogue output tile

  float bnl[4], bgt[4];
#pragma unroll
  for (int j = 0; j < 4; ++j) {
    const int c = h0 + wn * 64 + j * 16 + l16;
    bnl[j] = bias[c];
    bgt[j] = bias[512 + c];
  }

  if (final_mode) {
    // fp32 [256][64] per wn-half = 64KB; two passes, full-line (2x128B/row) stores
    float* ft = (float*)smem;
#pragma unroll
    for (int p = 0; p < 2; ++p) {
      if (wn == p) {
#pragma unroll
        for (int i = 0; i < 4; ++i)
#pragma unroll
          for (int r = 0; r < 4; ++r) {
            const int rl = wm * 64 + i * 16 + quad * 4 + r;
#pragma unroll
            for (int j = 0; j < 4; ++j) {
              float pn = acc[i][j][r] + bnl[j];
              float pg = acc[i][j + 4][r] + bgt[j];
              float g = 1.f / (1.f + __expf(-pg));
              unsigned int u = xsp[i][j][r >> 1];
              unsigned int bits = (r & 1) ? (u >> 16) : (u & 0xffffu);
              float xo = __uint_as_float(bits << 16);
              ft[rl * 64 + j * 16 + l16] = g * xo + (1.f - g) * fmaxf(pn, 0.f);
            }
          }
      }
      __syncthreads();
#pragma unroll
      for (int q = 0; q < 8; ++q) {
        const int rl = q * 32 + (tid >> 4);
        const int cc = (tid & 15) * 4;
        float4 v = *(const float4*)&ft[rl * 64 + cc];
        *(float4*)&outp[(size_t)(m0 + rl) * N_ + dir * H_ + h0 + p * 64 + cc] = v;
      }
      __syncthreads();
    }
  } else {
    // bf16 [256][128] = 64KB; one pass, full-line (2x128B/row) stores
    __hip_bfloat16* bt = (__hip_bfloat16*)smem;
#pragma unroll
    for (int i = 0; i < 4; ++i)
#pragma unroll
      for (int r = 0; r < 4; ++r) {
        const int rl = wm * 64 + i * 16 + quad * 4 + r;
#pragma unroll
        for (int j = 0; j < 4; ++j) {
          float pn = acc[i][j][r] + bnl[j];
          float pg = acc[i][j + 4][r] + bgt[j];
          float g = 1.f / (1.f + __expf(-pg));
          unsigned int u = xsp[i][j][r >> 1];
          unsigned int bits = (r & 1) ? (u >> 16) : (u & 0xffffu);
          float xo = __uint_as_float(bits << 16);
          bt[rl * 128 + wn * 64 + j * 16 + l16] =
              __float2bfloat16(g * xo + (1.f - g) * fmaxf(pn, 0.f));
        }
      }
    __syncthreads();
    const unsigned short* src = (const unsigned short*)smem;
#pragma unroll
    for (int p = 0; p < 8; ++p) {
      const int rl = p * 32 + (tid >> 4);
      const int cc = (tid & 15) * 8;             // 8 bf16 = 16B per lane
      int4 v = *(const int4*)(src + rl * 128 + cc);
      *(int4*)((unsigned short*)An + (size_t)(m0 + rl) * H_ + h0 + cc) = v;
    }
  }
}

extern "C" void kernel_launch(void* const* d_in, const int* in_sizes, int n_in,
                              void* d_out, int out_size, void* d_ws, size_t ws_size,
                              hipStream_t stream) {
  const float* inputs   = (const float*)d_in[0];
  // d_in[1] = masks (unused by reference)
  const float* fwd_pads = (const float*)d_in[2];
  const float* bwd_pads = (const float*)d_in[3];
  const float* fwd_ws_p = (const float*)d_in[4];
  const float* bwd_ws_p = (const float*)d_in[5];
  const float* fwd_hw_W = (const float*)d_in[6];
  const float* fwd_hw_b = (const float*)d_in[7];
  const float* bwd_hw_W = (const float*)d_in[8];
  const float* bwd_hw_b = (const float*)d_in[9];
  float* out = (float*)d_out;

  char* ws = (char*)d_ws;
  size_t off = 0;
  __hip_bfloat16* Wbf = (__hip_bfloat16*)(ws + off); off += (size_t)4194304 * 2;  // 8 matrices [1024,512]
  __hip_bfloat16* xa0f = (__hip_bfloat16*)(ws + off); off += (size_t)M_ * H_ * 2;
  __hip_bfloat16* xa0b = (__hip_bfloat16*)(ws + off); off += (size_t)M_ * H_ * 2;
  __hip_bfloat16* xa1f = (__hip_bfloat16*)(ws + off); off += (size_t)M_ * H_ * 2;
  __hip_bfloat16* xa1b = (__hip_bfloat16*)(ws + off); off += (size_t)M_ * H_ * 2;
  // total ~75 MiB

  // weights -> bf16 (fwd at 0, bwd at +2097152 elements), single launch
  cvt2_kernel<<<4096, 256, 0, stream>>>(fwd_hw_W, bwd_hw_W, Wbf, Wbf + (size_t)2097152);

  for (int l = 0; l < 2; ++l) {
    const float *inf, *inb;
    int instride;
    if (l == 0) { inf = inputs; inb = inputs; instride = H_; }
    else        { inf = out;    inb = out + H_; instride = N_; }  // read layer-0 output
    conv_kernel<<<dim3(8192, 2), 256, 0, stream>>>(
        inf, inb, instride,
        fwd_pads + (size_t)l * 4 * H_, bwd_pads + (size_t)l * 4 * H_,
        fwd_ws_p + l * 5, bwd_ws_p + l * 5,
        xa0f, xa0b);

    // highway iter 0 (writes bf16 x ping)
    hw_gemm<<<dim3(256, 1, 2), 512, 0, stream>>>(
        xa0f, xa0b,
        Wbf + (size_t)(l * 2) * 524288, Wbf + (size_t)2097152 + (size_t)(l * 2) * 524288,
        fwd_hw_b + (l * 2) * 1024, bwd_hw_b + (l * 2) * 1024,
        xa1f, xa1b, nullptr, 0);

    // highway iter 1 (final: writes d_out[l])
    hw_gemm<<<dim3(256, 1, 2), 512, 0, stream>>>(
        xa1f, xa1b,
        Wbf + (size_t)(l * 2 + 1) * 524288, Wbf + (size_t)2097152 + (size_t)(l * 2 + 1) * 524288,
        fwd_hw_b + (l * 2 + 1) * 1024, bwd_hw_b + (l * 2 + 1) * 1024,
        nullptr, nullptr, out + (size_t)l * M_ * N_, 1);
  }
}